// Round 14
// baseline (1317.038 us; speedup 1.0000x reference)
//
#include <hip/hip_runtime.h>
#include <math.h>

#define DMODEL 512
#define DINNER 1024
#define DSTATE 16
#define DTRANK 32
#define NLAYERS 6
#define BB 2
#define LT 512
#define LS 512

typedef __attribute__((ext_vector_type(8))) short bf16x8;
typedef __attribute__((ext_vector_type(8))) unsigned short u16x8;
typedef __attribute__((ext_vector_type(4))) float f32x4;

__device__ __forceinline__ unsigned short f2bf(float f) {
  unsigned u = __float_as_uint(f);
  u += 0x7fffu + ((u >> 16) & 1u);
  return (unsigned short)(u >> 16);
}
__device__ __forceinline__ float bf2f(unsigned short u) {
  return __uint_as_float((unsigned)u << 16);
}

// 0=none, 1=bias+relu, 2=bias, 3=bias+softplus
template<int EPI>
__device__ __forceinline__ float epi_apply(float acc, float b) {
  if (EPI == 1) { float v = acc + b; return v > 0.f ? v : 0.f; }
  if (EPI == 2) { return acc + b; }
  if (EPI == 3) { float v = acc + b; return fmaxf(v, 0.f) + log1pf(__expf(-fabsf(v))); }
  return acc;
}

// ---------------- fused weight conversion, one float4 per thread ----------------
__global__ __launch_bounds__(256) void cvt_all_kernel(
    const float* __restrict__ i0, const float* __restrict__ i1,
    const float* __restrict__ i2, const float* __restrict__ i3,
    const float* __restrict__ i4, const float* __restrict__ i5,
    const float* __restrict__ i6, const float* __restrict__ i7,
    const float* __restrict__ i8, const float* __restrict__ i9,
    unsigned short* __restrict__ outbase) {
  int i = blockIdx.x * 256 + threadIdx.x;
  if (i >= 8159232) return;
  const float* in; int off;
  if      (i < 1572864) { in = i0; off = i; }
  else if (i < 3145728) { in = i1; off = i - 1572864; }
  else if (i < 3244032) { in = i2; off = i - 3145728; }
  else if (i < 3342336) { in = i3; off = i - 3244032; }
  else if (i < 3391488) { in = i4; off = i - 3342336; }
  else if (i < 3440640) { in = i5; off = i - 3391488; }
  else if (i < 4227072) { in = i6; off = i - 3440640; }
  else if (i < 5013504) { in = i7; off = i - 4227072; }
  else if (i < 6586368) { in = i8; off = i - 5013504; }
  else                  { in = i9; off = i - 6586368; }
  float4 a = ((const float4*)in)[off];
  ushort4 o = make_ushort4(f2bf(a.x), f2bf(a.y), f2bf(a.z), f2bf(a.w));
  *(ushort4*)&outbase[(size_t)i * 4] = o;
}

// ---------------- embedding + PE (blocks 0..2047) and src->CATb (2048..2303) ----
__global__ __launch_bounds__(256) void embed_cat_kernel(const int* __restrict__ tgt,
    const float* __restrict__ emb, const float* __restrict__ src,
    float* __restrict__ X, unsigned short* __restrict__ Xb,
    unsigned short* __restrict__ CATb) {
  if (blockIdx.x < 2048) {
    int i = blockIdx.x * 256 + threadIdx.x;
    int d = i & (DMODEL - 1);
    int bt = i >> 9;
    int t = bt & (LT - 1);
    int tok = tgt[bt];
    float div = __expf((float)(d & ~1) * (-9.210340371976184f / (float)DMODEL));
    float ang = (float)t * div;
    float pe = (d & 1) ? cosf(ang) : sinf(ang);
    float v = emb[(size_t)tok * DMODEL + d] * 22.627416997969522f + pe;
    X[i] = v;
    Xb[i] = f2bf(v);
  } else {
    int i = (blockIdx.x - 2048) * 256 + threadIdx.x;   // u16x8 units over 2*512*512
    int c8 = (i & 63) * 8;
    int r = i >> 6;
    int b = r >> 9, l = r & 511;
    const float* s = src + ((size_t)b * 512 + l) * DMODEL + c8;
    float4 a = *(const float4*)s;
    float4 bq = *(const float4*)(s + 4);
    u16x8 o;
    o[0] = f2bf(a.x); o[1] = f2bf(a.y); o[2] = f2bf(a.z); o[3] = f2bf(a.w);
    o[4] = f2bf(bq.x); o[5] = f2bf(bq.y); o[6] = f2bf(bq.z); o[7] = f2bf(bq.w);
    *(u16x8*)&CATb[((size_t)b * 1024 + l) * DMODEL + c8] = o;
  }
}

// ---------------- MFMA GEMM 64x128 tile (bf16 A, bf16 W) ----------
// SPLIT: bf16 partials to Cb (+z*M*N).
template<int BK, int EPI, bool SPLIT, bool OUTB>
__global__ __launch_bounds__(256) void mgemmA(
    const unsigned short* __restrict__ A, const unsigned short* __restrict__ Bw,
    const float* __restrict__ bias, float* __restrict__ C,
    unsigned short* __restrict__ Cb, int M, int N, int K, int lda) {
  constexpr int PAD = BK + 8;
  constexpr int CHA = BK / 32;
  constexpr int CHB = BK / 16;
  __shared__ __align__(16) unsigned short As[64 * PAD];
  __shared__ __align__(16) unsigned short Bs[128 * PAD];
  const int tid = threadIdx.x;
  const int bn = blockIdx.x * 128;
  const int bm = blockIdx.y * 64;
  const int lane = tid & 63;
  const int w = tid >> 6;
  const int wr = (w >> 1) * 32;
  const int wc = (w & 1) * 64;
  const int l15 = lane & 15;
  const int l4 = lane >> 4;
  const int koff = l4 * 8;
  int kcnt = K, kbeg = 0;
  if (SPLIT) { kcnt = K / (int)gridDim.z; kbeg = blockIdx.z * kcnt; }
  const int nt = kcnt / BK;
  f32x4 acc[2][4] = {};

  int arow_[CHA], ak8_[CHA];
  const unsigned short* Ap[CHA];
#pragma unroll
  for (int i = 0; i < CHA; ++i) {
    int f = tid + 256 * i;
    arow_[i] = f / (BK / 8);
    ak8_[i] = (f % (BK / 8)) * 8;
    Ap[i] = A + (size_t)(bm + arow_[i]) * lda + kbeg + ak8_[i];
  }
  int brow_[CHB], bk8_[CHB];
  const unsigned short* Bp[CHB];
#pragma unroll
  for (int i = 0; i < CHB; ++i) {
    int f = tid + 256 * i;
    brow_[i] = f / (BK / 8);
    bk8_[i] = (f % (BK / 8)) * 8;
    Bp[i] = Bw + (size_t)(bn + brow_[i]) * K + kbeg + bk8_[i];
  }

  u16x8 av[CHA], bv[CHB];
#pragma unroll
  for (int i = 0; i < CHA; ++i) av[i] = *(const u16x8*)Ap[i];
#pragma unroll
  for (int i = 0; i < CHB; ++i) bv[i] = *(const u16x8*)Bp[i];

  for (int t = 0; t < nt; ++t) {
    __syncthreads();
#pragma unroll
    for (int i = 0; i < CHA; ++i) *(u16x8*)&As[arow_[i] * PAD + ak8_[i]] = av[i];
#pragma unroll
    for (int i = 0; i < CHB; ++i) *(u16x8*)&Bs[brow_[i] * PAD + bk8_[i]] = bv[i];
    if (t + 1 < nt) {
      int ko = (t + 1) * BK;
#pragma unroll
      for (int i = 0; i < CHA; ++i) av[i] = *(const u16x8*)(Ap[i] + ko);
#pragma unroll
      for (int i = 0; i < CHB; ++i) bv[i] = *(const u16x8*)(Bp[i] + ko);
    }
    __syncthreads();
#pragma unroll
    for (int kk = 0; kk < BK / 32; ++kk) {
      bf16x8 afr[2], bfr[4];
#pragma unroll
      for (int i = 0; i < 2; ++i)
        afr[i] = *(const bf16x8*)&As[(wr + i * 16 + l15) * PAD + kk * 32 + koff];
#pragma unroll
      for (int j = 0; j < 4; ++j)
        bfr[j] = *(const bf16x8*)&Bs[(wc + j * 16 + l15) * PAD + kk * 32 + koff];
#pragma unroll
      for (int fr = 0; fr < 2; ++fr)
#pragma unroll
        for (int fc = 0; fc < 4; ++fc)
          acc[fr][fc] = __builtin_amdgcn_mfma_f32_16x16x32_bf16(
              afr[fr], bfr[fc], acc[fr][fc], 0, 0, 0);
    }
  }

  if (SPLIT) {
    unsigned short* Pz = Cb + (size_t)blockIdx.z * M * N;
#pragma unroll
    for (int fc = 0; fc < 4; ++fc) {
      int col = bn + wc + fc * 16 + l15;
#pragma unroll
      for (int fr = 0; fr < 2; ++fr) {
        int row0 = bm + wr + fr * 16 + l4 * 4;
#pragma unroll
        for (int r = 0; r < 4; ++r)
          Pz[(size_t)(row0 + r) * N + col] = f2bf(acc[fr][fc][r]);
      }
    }
  } else {
#pragma unroll
    for (int fc = 0; fc < 4; ++fc) {
      int col = bn + wc + fc * 16 + l15;
      float bvs = (EPI != 0) ? bias[col] : 0.f;
#pragma unroll
      for (int fr = 0; fr < 2; ++fr) {
        int row0 = bm + wr + fr * 16 + l4 * 4;
#pragma unroll
        for (int r = 0; r < 4; ++r) {
          float v = epi_apply<EPI>(acc[fr][fc][r], bvs);
          if (OUTB) Cb[(size_t)(row0 + r) * N + col] = f2bf(v);
          else      C[(size_t)(row0 + r) * N + col] = v;
        }
      }
    }
  }
}

// ---------------- MFMA GEMM 64x64 tile (bf16 A, bf16 W) ----------------
template<int BK, int EPI, bool SPLIT, bool OUTB>
__global__ __launch_bounds__(256) void mgemm(
    const unsigned short* __restrict__ A, const unsigned short* __restrict__ Bw,
    const float* __restrict__ bias, float* __restrict__ C,
    unsigned short* __restrict__ Cb, int M, int N, int K, int lda) {
  constexpr int PAD = BK + 8;
  constexpr int CH = BK / 32;
  __shared__ __align__(16) unsigned short As[64 * PAD];
  __shared__ __align__(16) unsigned short Bs[64 * PAD];
  const int tid = threadIdx.x;
  const int bn = blockIdx.x * 64;
  const int bm = blockIdx.y * 64;
  const int lane = tid & 63;
  const int w = tid >> 6;
  const int wr = (w >> 1) * 32;
  const int wc = (w & 1) * 32;
  const int l15 = lane & 15;
  const int l4 = lane >> 4;
  const int koff = l4 * 8;
  int kcnt = K, kbeg = 0;
  if (SPLIT) { kcnt = K / (int)gridDim.z; kbeg = blockIdx.z * kcnt; }
  const int nt = kcnt / BK;
  f32x4 acc[2][2] = {};

  int row_[CH], k8_[CH];
  const unsigned short *Ap[CH], *Bp[CH];
#pragma unroll
  for (int i = 0; i < CH; ++i) {
    int f = tid + 256 * i;
    row_[i] = f / (BK / 8);
    k8_[i] = (f % (BK / 8)) * 8;
    Ap[i] = A + (size_t)(bm + row_[i]) * lda + kbeg + k8_[i];
    Bp[i] = Bw + (size_t)(bn + row_[i]) * K + kbeg + k8_[i];
  }

  u16x8 av[CH], bv[CH];
#pragma unroll
  for (int i = 0; i < CH; ++i) { av[i] = *(const u16x8*)Ap[i]; bv[i] = *(const u16x8*)Bp[i]; }

  for (int t = 0; t < nt; ++t) {
    __syncthreads();
#pragma unroll
    for (int i = 0; i < CH; ++i) {
      *(u16x8*)&As[row_[i] * PAD + k8_[i]] = av[i];
      *(u16x8*)&Bs[row_[i] * PAD + k8_[i]] = bv[i];
    }
    if (t + 1 < nt) {
      int ko = (t + 1) * BK;
#pragma unroll
      for (int i = 0; i < CH; ++i) {
        av[i] = *(const u16x8*)(Ap[i] + ko);
        bv[i] = *(const u16x8*)(Bp[i] + ko);
      }
    }
    __syncthreads();
#pragma unroll
    for (int kk = 0; kk < CH; ++kk) {
      bf16x8 afr[2], bfr[2];
#pragma unroll
      for (int i = 0; i < 2; ++i) {
        afr[i] = *(const bf16x8*)&As[(wr + i * 16 + l15) * PAD + kk * 32 + koff];
        bfr[i] = *(const bf16x8*)&Bs[(wc + i * 16 + l15) * PAD + kk * 32 + koff];
      }
#pragma unroll
      for (int fr = 0; fr < 2; ++fr)
#pragma unroll
        for (int fc = 0; fc < 2; ++fc)
          acc[fr][fc] = __builtin_amdgcn_mfma_f32_16x16x32_bf16(
              afr[fr], bfr[fc], acc[fr][fc], 0, 0, 0);
    }
  }

  if (SPLIT) {
    float* Pz = C + (size_t)blockIdx.z * M * N;
#pragma unroll
    for (int fc = 0; fc < 2; ++fc) {
      int col = bn + wc + fc * 16 + l15;
#pragma unroll
      for (int fr = 0; fr < 2; ++fr) {
        int row0 = bm + wr + fr * 16 + l4 * 4;
#pragma unroll
        for (int r = 0; r < 4; ++r)
          Pz[(size_t)(row0 + r) * N + col] = acc[fr][fc][r];
      }
    }
  } else {
#pragma unroll
    for (int fc = 0; fc < 2; ++fc) {
      int col = bn + wc + fc * 16 + l15;
      float bvs = (EPI != 0) ? bias[col] : 0.f;
#pragma unroll
      for (int fr = 0; fr < 2; ++fr) {
        int row0 = bm + wr + fr * 16 + l4 * 4;
#pragma unroll
        for (int r = 0; r < 4; ++r) {
          float v = epi_apply<EPI>(acc[fr][fc][r], bvs);
          if (OUTB) Cb[(size_t)(row0 + r) * N + col] = f2bf(v);
          else      C[(size_t)(row0 + r) * N + col] = v;
        }
      }
    }
  }
}

// ---------------- fused conv(k=4)+silu + xproj (N=64) ----------------
// Block = 2 rows. Phase 1: conv+silu -> bf16 XCb + fp32 LDS.
// Phase 2: xproj row-dot (2 threads/output, shfl combine) -> fp32 XP[M][64].
__global__ __launch_bounds__(256) void conv_xproj_kernel(
    const unsigned short* __restrict__ xzb, const float* __restrict__ w,
    const float* __restrict__ bias, const unsigned short* __restrict__ xpw,
    unsigned short* __restrict__ outb, float* __restrict__ XP, int L) {
  __shared__ float XCf[2][1024];
  const int tid = threadIdx.x;
  const int grow0 = blockIdx.x * 2;
  const int b = grow0 / L;
  const int t0 = grow0 - b * L;
  {
    int r = tid >> 7;                 // 0..1
    int d8 = (tid & 127) * 8;
    int t = t0 + r;
    const unsigned short* col = xzb + ((size_t)b * L) * (2 * DINNER) + d8;
    float acc[8];
    float4 wv[8];
#pragma unroll
    for (int j = 0; j < 8; ++j) {
      acc[j] = bias[d8 + j];
      wv[j] = *(const float4*)(w + (size_t)(d8 + j) * 4);
    }
#pragma unroll
    for (int k = 0; k < 4; ++k) {
      int tt = t - 3 + k;
      if (tt >= 0) {
        u16x8 v = *(const u16x8*)(col + (size_t)tt * (2 * DINNER));
        float wk[8] = {
          k == 0 ? wv[0].x : k == 1 ? wv[0].y : k == 2 ? wv[0].z : wv[0].w,
          k == 0 ? wv[1].x : k == 1 ? wv[1].y : k == 2 ? wv[1].z : wv[1].w,
          k == 0 ? wv[2].x : k == 1 ? wv[2].y : k == 2 ? wv[2].z : wv[2].w,
          k == 0 ? wv[3].x : k == 1 ? wv[3].y : k == 2 ? wv[3].z : wv[3].w,
          k == 0 ? wv[4].x : k == 1 ? wv[4].y : k == 2 ? wv[4].z : wv[4].w,
          k == 0 ? wv[5].x : k == 1 ? wv[5].y : k == 2 ? wv[5].z : wv[5].w,
          k == 0 ? wv[6].x : k == 1 ? wv[6].y : k == 2 ? wv[6].z : wv[6].w,
          k == 0 ? wv[7].x : k == 1 ? wv[7].y : k == 2 ? wv[7].z : wv[7].w };
#pragma unroll
        for (int j = 0; j < 8; ++j) acc[j] = fmaf(bf2f(v[j]), wk[j], acc[j]);
      }
    }
    u16x8 o;
#pragma unroll
    for (int j = 0; j < 8; ++j) {
      float sig = 1.f / (1.f + __expf(-acc[j]));
      float xv = acc[j] * sig;
      o[j] = f2bf(xv);
      XCf[r][d8 + j] = xv;
    }
    *(u16x8*)&outb[(size_t)(b * L + t) * DINNER + d8] = o;
  }
  __syncthreads();
  // phase 2: 128 outputs (2 rows x 64 cols), 2 threads each over K halves
  int oid = tid >> 1, half = tid & 1;
  int r = oid >> 6, n = oid & 63;
  const unsigned short* wrow = xpw + (size_t)n * 1024 + half * 512;
  const float* xr = &XCf[r][half * 512];
  float a0 = 0.f, a1 = 0.f, a2 = 0.f, a3 = 0.f;
  for (int k8 = 0; k8 < 64; k8 += 4) {
    u16x8 w0 = *(const u16x8*)(wrow + (k8 + 0) * 8);
    u16x8 w1 = *(const u16x8*)(wrow + (k8 + 1) * 8);
    u16x8 w2 = *(const u16x8*)(wrow + (k8 + 2) * 8);
    u16x8 w3 = *(const u16x8*)(wrow + (k8 + 3) * 8);
    const float* x0 = xr + (k8 + 0) * 8;
    const float* x1 = xr + (k8 + 1) * 8;
    const float* x2 = xr + (k8 + 2) * 8;
    const float* x3 = xr + (k8 + 3) * 8;
#pragma unroll
    for (int j = 0; j < 8; ++j) {
      a0 = fmaf(x0[j], bf2f(w0[j]), a0);
      a1 = fmaf(x1[j], bf2f(w1[j]), a1);
      a2 = fmaf(x2[j], bf2f(w2[j]), a2);
      a3 = fmaf(x3[j], bf2f(w3[j]), a3);
    }
  }
  float acc = (a0 + a1) + (a2 + a3);
  acc += __shfl_xor(acc, 1);
  if (!half) XP[(size_t)(grow0 + r) * 64 + n] = acc;
}

// ---------------- chunked selective scan with inline dt-projection ----------------
// Stages XP rows directly; dt[t] = softplus(dot(row[0:32], dtw[d]) + dtb[d]).
__global__ __launch_bounds__(256) void scan_pass1(
    const float* __restrict__ XP, const unsigned short* __restrict__ u,
    const float* __restrict__ Alog, const float* __restrict__ dtw,
    const float* __restrict__ dtb, float* __restrict__ P, float* __restrict__ S,
    int L, int CL) {
  __shared__ float DBL8[32][64];
  const int tid = threadIdx.x;
  const int d = blockIdx.x * 256 + tid;
  const int b = blockIdx.y;
  const int c = blockIdx.z;
  const int t0 = c * CL;
  if (tid < CL * 8) {
    int t = tid >> 3, j8 = (tid & 7) * 8;
    const float* p = XP + ((size_t)b * L + t0 + t) * 64 + j8;
    float4 a = *(const float4*)p;
    float4 bq = *(const float4*)(p + 4);
    DBL8[t][j8 + 0] = a.x; DBL8[t][j8 + 1] = a.y;
    DBL8[t][j8 + 2] = a.z; DBL8[t][j8 + 3] = a.w;
    DBL8[t][j8 + 4] = bq.x; DBL8[t][j8 + 5] = bq.y;
    DBL8[t][j8 + 6] = bq.z; DBL8[t][j8 + 7] = bq.w;
  }
  float A[16];
#pragma unroll
  for (int j = 0; j < 4; ++j) {
    float4 a4 = *(const float4*)(Alog + d * 16 + j * 4);
    A[j * 4 + 0] = -__expf(a4.x); A[j * 4 + 1] = -__expf(a4.y);
    A[j * 4 + 2] = -__expf(a4.z); A[j * 4 + 3] = -__expf(a4.w);
  }
  float wreg[32];
#pragma unroll
  for (int j = 0; j < 8; ++j) {
    float4 w4 = *(const float4*)(dtw + (size_t)d * 32 + j * 4);
    wreg[j*4+0] = w4.x; wreg[j*4+1] = w4.y; wreg[j*4+2] = w4.z; wreg[j*4+3] = w4.w;
  }
  float dtbv = dtb[d];
  float h[16], Pp[16];
#pragma unroll
  for (int n = 0; n < 16; ++n) { h[n] = 0.f; Pp[n] = 1.f; }
  const unsigned short* up = u + ((size_t)b * L + t0) * DINNER + d;
  __syncthreads();
  for (int t = 0; t < CL; ++t) {
    float dtraw = dtbv;
#pragma unroll
    for (int k8 = 0; k8 < 8; ++k8) {
      float4 q = *(const float4*)&DBL8[t][k8 * 4];
      dtraw = fmaf(q.x, wreg[k8*4+0], dtraw);
      dtraw = fmaf(q.y, wreg[k8*4+1], dtraw);
      dtraw = fmaf(q.z, wreg[k8*4+2], dtraw);
      dtraw = fmaf(q.w, wreg[k8*4+3], dtraw);
    }
    float dtv = fmaxf(dtraw, 0.f) + log1pf(__expf(-fabsf(dtraw)));
    float uv = bf2f(up[(size_t)t * DINNER]);
    float du = dtv * uv;
    float Bv[16];
#pragma unroll
    for (int j = 0; j < 4; ++j) {
      float4 b4 = *(const float4*)&DBL8[t][32 + j * 4];
      Bv[j*4+0] = b4.x; Bv[j*4+1] = b4.y; Bv[j*4+2] = b4.z; Bv[j*4+3] = b4.w;
    }
#pragma unroll
    for (int n = 0; n < 16; ++n) {
      float dA = __expf(dtv * A[n]);
      Pp[n] *= dA;
      h[n] = fmaf(dA, h[n], du * Bv[n]);
    }
  }
  size_t base = (size_t)c * 32768 + ((size_t)(b * 1024 + d) << 4);
#pragma unroll
  for (int j = 0; j < 4; ++j) {
    *(float4*)&P[base + j * 4] = make_float4(Pp[j*4], Pp[j*4+1], Pp[j*4+2], Pp[j*4+3]);
    *(float4*)&S[base + j * 4] = make_float4(h[j*4], h[j*4+1], h[j*4+2], h[j*4+3]);
  }
}

// pass2: inline dt + chunk-prefix; writes compact bf16 y.
__global__ __launch_bounds__(256) void scan_pass2(
    const float* __restrict__ XP, const unsigned short* __restrict__ u,
    const unsigned short* __restrict__ xzb, const float* __restrict__ Alog,
    const float* __restrict__ dtw, const float* __restrict__ dtb,
    const float* __restrict__ Dsk, const float* __restrict__ P,
    const float* __restrict__ S, unsigned short* __restrict__ ysb,
    int L, int CL, int c0) {
  __shared__ float DBL8[32][64];
  const int tid = threadIdx.x;
  const int d = blockIdx.x * 256 + tid;
  const int b = blockIdx.y;
  const int c = blockIdx.z + c0;
  const int t0 = c * CL;
  if (tid < CL * 8) {
    int t = tid >> 3, j8 = (tid & 7) * 8;
    const float* p = XP + ((size_t)b * L + t0 + t) * 64 + j8;
    float4 a = *(const float4*)p;
    float4 bq = *(const float4*)(p + 4);
    DBL8[t][j8 + 0] = a.x; DBL8[t][j8 + 1] = a.y;
    DBL8[t][j8 + 2] = a.z; DBL8[t][j8 + 3] = a.w;
    DBL8[t][j8 + 4] = bq.x; DBL8[t][j8 + 5] = bq.y;
    DBL8[t][j8 + 6] = bq.z; DBL8[t][j8 + 7] = bq.w;
  }
  float A[16];
#pragma unroll
  for (int j = 0; j < 4; ++j) {
    float4 a4 = *(const float4*)(Alog + d * 16 + j * 4);
    A[j * 4 + 0] = -__expf(a4.x); A[j * 4 + 1] = -__expf(a4.y);
    A[j * 4 + 2] = -__expf(a4.z); A[j * 4 + 3] = -__expf(a4.w);
  }
  float wreg[32];
#pragma unroll
  for (int j = 0; j < 8; ++j) {
    float4 w4 = *(const float4*)(dtw + (size_t)d * 32 + j * 4);
    wreg[j*4+0] = w4.x; wreg[j*4+1] = w4.y; wreg[j*4+2] = w4.z; wreg[j*4+3] = w4.w;
  }
  float dtbv = dtb[d];
  float h[16];
#pragma unroll
  for (int n = 0; n < 16; ++n) h[n] = 0.f;
  size_t sbase = (size_t)(b * 1024 + d) << 4;
  for (int cc = 0; cc < c; ++cc) {
    size_t bb = (size_t)cc * 32768 + sbase;
#pragma unroll
    for (int j = 0; j < 4; ++j) {
      float4 p4 = *(const float4*)&P[bb + j * 4];
      float4 s4 = *(const float4*)&S[bb + j * 4];
      h[j*4+0] = fmaf(p4.x, h[j*4+0], s4.x);
      h[j*4+1] = fmaf(p4.y, h[j*4+1], s4.y);
      h[j*4+2] = fmaf(p4.z, h[j*4+2], s4.z);
      h[j*4+3] = fmaf(p4.w, h[j*4+3], s4.w);
    }
  }
  float Dv = Dsk[d];
  const unsigned short* up = u + ((size_t)b * L + t0) * DINNER + d;
  const unsigned short* zp = xzb + ((size_t)b * L + t0) * (2 * DINNER) + DINNER + d;
  unsigned short* yp = ysb + ((size_t)(b * 512) + (t0 - c0 * CL)) * DINNER + d;
  __syncthreads();
  for (int t = 0; t < CL; ++t) {
    float dtraw = dtbv;
#pragma unroll
    for (int k8 = 0; k8 < 8; ++k8) {
      float4 q = *(const float4*)&DBL8[t][k8 * 4];
      dtraw = fmaf(q.x, wreg[k8*4+0], dtraw);
      dtraw = fmaf(q.y, wreg[k8*4+1], dtraw);
      dtraw = fmaf(q.z, wreg[k8*4+2], dtraw);
      dtraw = fmaf(q.w, wreg[k8*4+3], dtraw);
    }
    float dtv = fmaxf(dtraw, 0.f) + log1pf(__expf(-fabsf(dtraw)));
    float uv = bf2f(up[(size_t)t * DINNER]);
    float zv = bf2f(zp[(size_t)t * (2 * DINNER)]);
    float du = dtv * uv;
    float Bv[16], Cv[16];
#pragma unroll
    for (int j = 0; j < 4; ++j) {
      float4 b4 = *(const float4*)&DBL8[t][32 + j * 4];
      float4 c4 = *(const float4*)&DBL8[t][48 + j * 4];
      Bv[j*4+0] = b4.x; Bv[j*4+1] = b4.y; Bv[j*4+2] = b4.z; Bv[j*4+3] = b4.w;
      Cv[j*4+0] = c4.x; Cv[j*4+1] = c4.y; Cv[j*4+2] = c4.z; Cv[j*4+3] = c4.w;
    }
    float y = 0.f;
#pragma unroll
    for (int n = 0; n < 16; ++n) {
      float dA = __expf(dtv * A[n]);
      h[n] = fmaf(dA, h[n], du * Bv[n]);
      y = fmaf(h[n], Cv[n], y);
    }
    float sig = 1.f / (1.f + __expf(-zv));
    yp[(size_t)t * DINNER] = f2bf((y + uv * Dv) * (zv * sig));
  }
}

// ---------------- fused split-K reduce (bf16 partials) + residual + LayerNorm ----
template<int NZ, int EPI>
__global__ __launch_bounds__(64) void ln_red_kernel(
    const float* __restrict__ res, const unsigned short* __restrict__ Pb,
    const float* __restrict__ bias, const float* __restrict__ g,
    const float* __restrict__ be, float* __restrict__ out,
    unsigned short* __restrict__ outb, int row_scale, int row_off) {
  int r = blockIdx.x;
  int b = r >> 9, t = r & 511;
  int lane = threadIdx.x;
  const float* rp = res + (size_t)r * DMODEL;
  size_t ob = ((size_t)(b * row_scale + row_off + t)) * DMODEL;
  float v[8];
  float s = 0.f, ss = 0.f;
#pragma unroll
  for (int j = 0; j < 8; ++j) {
    int col = lane + j * 64;
    float acc = 0.f;
#pragma unroll
    for (int z = 0; z < NZ; ++z)
      acc += bf2f(Pb[(size_t)z * 524288 + (size_t)r * DMODEL + col]);
    float bv = (EPI != 0) ? bias[col] : 0.f;
    float x = rp[col] + epi_apply<EPI>(acc, bv);
    v[j] = x; s += x; ss += x * x;
  }
#pragma unroll
  for (int o = 32; o > 0; o >>= 1) { s += __shfl_xor(s, o); ss += __shfl_xor(ss, o); }
  float m = s * (1.f / 512.f);
  float var = ss * (1.f / 512.f) - m * m;
  float rs = rsqrtf(var + 1e-6f);
#pragma unroll
  for (int j = 0; j < 8; ++j) {
    int col = lane + j * 64;
    float o2 = (v[j] - m) * rs * g[col] + be[col];
    out[(size_t)r * DMODEL + col] = o2;
    outb[ob + col] = f2bf(o2);
  }
}

// ---------------- final LayerNorm ----------------
__global__ __launch_bounds__(64) void ln_final_kernel(
    const float* __restrict__ res, const float* __restrict__ g,
    const float* __restrict__ be, float* __restrict__ out) {
  int r = blockIdx.x;
  int lane = threadIdx.x;
  const float* rp = res + (size_t)r * DMODEL;
  float v[8];
  float s = 0.f, ss = 0.f;
#pragma unroll
  for (int j = 0; j < 8; ++j) {
    float x = rp[lane + j * 64];
    v[j] = x; s += x; ss += x * x;
  }
#pragma unroll
  for (int o = 32; o > 0; o >>= 1) { s += __shfl_xor(s, o); ss += __shfl_xor(ss, o); }
  float m = s * (1.f / 512.f);
  float var = ss * (1.f / 512.f) - m * m;
  float rs = rsqrtf(var + 1e-6f);
#pragma unroll
  for (int j = 0; j < 8; ++j) {
    int c = lane + j * 64;
    out[(size_t)r * DMODEL + c] = (v[j] - m) * rs * g[c] + be[c];
  }
}

// ---------------- orchestration ----------------
extern "C" void kernel_launch(void* const* d_in, const int* in_sizes, int n_in,
                              void* d_out, int out_size, void* d_ws, size_t ws_size,
                              hipStream_t stream) {
  (void)in_sizes; (void)n_in; (void)out_size; (void)ws_size;
  const float* src      = (const float*)d_in[0];
  const int*   tgt      = (const int*)d_in[1];
  const float* emb      = (const float*)d_in[2];
  const float* in_w_s   = (const float*)d_in[3];
  const float* conv_w_s = (const float*)d_in[4];
  const float* conv_b_s = (const float*)d_in[5];
  const float* xproj_s  = (const float*)d_in[6];
  const float* dtw_s    = (const float*)d_in[7];
  const float* dtb_s    = (const float*)d_in[8];
  const float* Alog_s   = (const float*)d_in[9];
  const float* D_s      = (const float*)d_in[10];
  const float* outw_s   = (const float*)d_in[11];
  const float* in_w_c   = (const float*)d_in[12];
  const float* conv_w_c = (const float*)d_in[13];
  const float* conv_b_c = (const float*)d_in[14];
  const float* xproj_c  = (const float*)d_in[15];
  const float* dtw_c    = (const float*)d_in[16];
  const float* dtb_c    = (const float*)d_in[17];
  const float* Alog_c   = (const float*)d_in[18];
  const float* D_c      = (const float*)d_in[19];
  const float* outw_c   = (const float*)d_in[20];
  const float* ffn_w1   = (const float*)d_in[21];
  const float* ffn_b1   = (const float*)d_in[22];
  const float* ffn_w2   = (const float*)d_in[23];
  const float* ffn_b2   = (const float*)d_in[24];
  const float* ln_g     = (const float*)d_in[25];
  const float* ln_b     = (const float*)d_in[26];
  const float* fin_g    = (const float*)d_in[27];
  const float* fin_b    = (const float*)d_in[28];

  // ---- workspace layout ----
  float* ws   = (float*)d_ws;
  float* X    = ws;                   // 524288
  float* XP   = X + 524288;           // 131072 (xproj output, fp32 M x 64)
  float* SC_P = XP + 131072;          // 1048576 (scan P)
  float* SC_S = SC_P + 1048576;       // 1048576 (scan S)
  unsigned short* U = (unsigned short*)(SC_S + 1048576);
  unsigned short* Xb   = U;                   // 524288
  unsigned short* CATb = Xb + 524288;         // 1048576
  unsigned short* XCb  = CATb + 1048576;      // 2097152
  unsigned short* XZb  = XCb + 2097152;       // 4194304
  unsigned short* YSb  = XZb + 4194304;       // 1048576
  unsigned short* XZPb = YSb + 1048576;       // 4194304 (out/ffn2 bf16 partials, z=8)
  unsigned short* WB   = XZPb + 4194304;
  unsigned short* inwsb = WB;                 // 6291456
  unsigned short* inwcb = inwsb + 6291456;    // 6291456
  unsigned short* xpsb  = inwcb + 6291456;    // 393216
  unsigned short* xpcb  = xpsb + 393216;      // 393216
  unsigned short* dtwsb = xpcb + 393216;      // 196608 (unused; cvt layout)
  unsigned short* dtwcb = dtwsb + 196608;     // 196608 (unused)
  unsigned short* owsb  = dtwcb + 196608;     // 3145728
  unsigned short* owcb  = owsb + 3145728;     // 3145728
  unsigned short* f1b   = owcb + 3145728;     // 6291456
  unsigned short* f2b   = f1b + 6291456;      // 6291456

  cvt_all_kernel<<<31872, 256, 0, stream>>>(
      in_w_s, in_w_c, xproj_s, xproj_c, dtw_s, dtw_c, outw_s, outw_c,
      ffn_w1, ffn_w2, WB);
  embed_cat_kernel<<<2304, 256, 0, stream>>>(tgt, emb, src, X, Xb, CATb);

  for (int i = 0; i < NLAYERS; ++i) {
    // ---------- self mamba (L = 512, CL = 16, 32 chunks) ----------
    mgemm<64, 0, false, true><<<dim3(32, 16), 256, 0, stream>>>(
        Xb, inwsb + (size_t)i * 1048576, nullptr, nullptr, XZb, 1024, 2048, 512, 512);
    conv_xproj_kernel<<<512, 256, 0, stream>>>(
        XZb, conv_w_s + (size_t)i * 4096, conv_b_s + (size_t)i * 1024,
        xpsb + (size_t)i * 65536, XCb, XP, 512);
    scan_pass1<<<dim3(4, 2, 32), 256, 0, stream>>>(
        XP, XCb, Alog_s + (size_t)i * 16384, dtw_s + (size_t)i * 32768,
        dtb_s + (size_t)i * 1024, SC_P, SC_S, 512, 16);
    scan_pass2<<<dim3(4, 2, 32), 256, 0, stream>>>(
        XP, XCb, XZb, Alog_s + (size_t)i * 16384, dtw_s + (size_t)i * 32768,
        dtb_s + (size_t)i * 1024, D_s + (size_t)i * 1024, SC_P, SC_S, YSb, 512, 16, 0);
    mgemmA<64, 0, true, false><<<dim3(4, 16, 8), 256, 0, stream>>>(
        YSb, owsb + (size_t)i * 524288, nullptr, nullptr, XZPb, 1024, 512, 1024, 1024);
    ln_red_kernel<8, 0><<<1024, 64, 0, stream>>>(
        X, XZPb, nullptr, ln_g + (size_t)(i * 3 + 0) * 512,
        ln_b + (size_t)(i * 3 + 0) * 512, X, CATb, 1024, 512);

    // ---------- cross mamba (L = 1024, CL = 32; y for last 512 t only) ----------
    mgemmA<64, 0, false, true><<<dim3(16, 32), 256, 0, stream>>>(
        CATb, inwcb + (size_t)i * 1048576, nullptr, nullptr, XZb, 2048, 2048, 512, 512);
    conv_xproj_kernel<<<1024, 256, 0, stream>>>(
        XZb, conv_w_c + (size_t)i * 4096, conv_b_c + (size_t)i * 1024,
        xpcb + (size_t)i * 65536, XCb, XP, 1024);
    scan_pass1<<<dim3(4, 2, 32), 256, 0, stream>>>(
        XP, XCb, Alog_c + (size_t)i * 16384, dtw_c + (size_t)i * 32768,
        dtb_c + (size_t)i * 1024, SC_P, SC_S, 1024, 32);
    scan_pass2<<<dim3(4, 2, 16), 256, 0, stream>>>(
        XP, XCb, XZb, Alog_c + (size_t)i * 16384, dtw_c + (size_t)i * 32768,
        dtb_c + (size_t)i * 1024, D_c + (size_t)i * 1024, SC_P, SC_S, YSb, 1024, 32, 16);
    mgemmA<64, 0, true, false><<<dim3(4, 16, 8), 256, 0, stream>>>(
        YSb, owcb + (size_t)i * 524288, nullptr, nullptr, XZPb, 1024, 512, 1024, 1024);
    ln_red_kernel<8, 0><<<1024, 64, 0, stream>>>(
        X, XZPb, nullptr, ln_g + (size_t)(i * 3 + 1) * 512,
        ln_b + (size_t)(i * 3 + 1) * 512, X, Xb, 512, 0);

    // ---------- FFN ----------
    mgemm<64, 1, false, true><<<dim3(32, 16), 256, 0, stream>>>(
        Xb, f1b + (size_t)i * 1048576, ffn_b1 + (size_t)i * 2048, nullptr, XZb,
        1024, 2048, 512, 512);
    mgemmA<64, 0, true, false><<<dim3(4, 16, 8), 256, 0, stream>>>(
        XZb, f2b + (size_t)i * 1048576, nullptr, nullptr, XZPb, 1024, 512, 2048, 2048);
    ln_red_kernel<8, 2><<<1024, 64, 0, stream>>>(
        X, XZPb, ffn_b2 + (size_t)i * 512, ln_g + (size_t)(i * 3 + 2) * 512,
        ln_b + (size_t)(i * 3 + 2) * 512, X, Xb, 512, 0);
  }

  ln_final_kernel<<<1024, 64, 0, stream>>>(X, fin_g, fin_b, (float*)d_out);
}

// Round 15
// 1130.067 us; speedup vs baseline: 1.1655x; 1.1655x over previous
//
#include <hip/hip_runtime.h>
#include <math.h>

#define DMODEL 512
#define DINNER 1024
#define DSTATE 16
#define DTRANK 32
#define NLAYERS 6
#define BB 2
#define LT 512
#define LS 512

typedef __attribute__((ext_vector_type(8))) short bf16x8;
typedef __attribute__((ext_vector_type(8))) unsigned short u16x8;
typedef __attribute__((ext_vector_type(4))) float f32x4;

__device__ __forceinline__ unsigned short f2bf(float f) {
  unsigned u = __float_as_uint(f);
  u += 0x7fffu + ((u >> 16) & 1u);
  return (unsigned short)(u >> 16);
}
__device__ __forceinline__ float bf2f(unsigned short u) {
  return __uint_as_float((unsigned)u << 16);
}

// 0=none, 1=bias+relu, 2=bias, 3=bias+softplus
template<int EPI>
__device__ __forceinline__ float epi_apply(float acc, float b) {
  if (EPI == 1) { float v = acc + b; return v > 0.f ? v : 0.f; }
  if (EPI == 2) { return acc + b; }
  if (EPI == 3) { float v = acc + b; return fmaxf(v, 0.f) + log1pf(__expf(-fabsf(v))); }
  return acc;
}

// ---------------- fused weight conversion, one float4 per thread ----------------
__global__ __launch_bounds__(256) void cvt_all_kernel(
    const float* __restrict__ i0, const float* __restrict__ i1,
    const float* __restrict__ i2, const float* __restrict__ i3,
    const float* __restrict__ i4, const float* __restrict__ i5,
    const float* __restrict__ i6, const float* __restrict__ i7,
    const float* __restrict__ i8, const float* __restrict__ i9,
    unsigned short* __restrict__ outbase) {
  int i = blockIdx.x * 256 + threadIdx.x;
  if (i >= 8159232) return;
  const float* in; int off;
  if      (i < 1572864) { in = i0; off = i; }
  else if (i < 3145728) { in = i1; off = i - 1572864; }
  else if (i < 3244032) { in = i2; off = i - 3145728; }
  else if (i < 3342336) { in = i3; off = i - 3244032; }
  else if (i < 3391488) { in = i4; off = i - 3342336; }
  else if (i < 3440640) { in = i5; off = i - 3391488; }
  else if (i < 4227072) { in = i6; off = i - 3440640; }
  else if (i < 5013504) { in = i7; off = i - 4227072; }
  else if (i < 6586368) { in = i8; off = i - 5013504; }
  else                  { in = i9; off = i - 6586368; }
  float4 a = ((const float4*)in)[off];
  ushort4 o = make_ushort4(f2bf(a.x), f2bf(a.y), f2bf(a.z), f2bf(a.w));
  *(ushort4*)&outbase[(size_t)i * 4] = o;
}

// ---------------- embedding + PE (blocks 0..2047) and src->CATb (2048..2303) ----
__global__ __launch_bounds__(256) void embed_cat_kernel(const int* __restrict__ tgt,
    const float* __restrict__ emb, const float* __restrict__ src,
    float* __restrict__ X, unsigned short* __restrict__ Xb,
    unsigned short* __restrict__ CATb) {
  if (blockIdx.x < 2048) {
    int i = blockIdx.x * 256 + threadIdx.x;
    int d = i & (DMODEL - 1);
    int bt = i >> 9;
    int t = bt & (LT - 1);
    int tok = tgt[bt];
    float div = __expf((float)(d & ~1) * (-9.210340371976184f / (float)DMODEL));
    float ang = (float)t * div;
    float pe = (d & 1) ? cosf(ang) : sinf(ang);
    float v = emb[(size_t)tok * DMODEL + d] * 22.627416997969522f + pe;
    X[i] = v;
    Xb[i] = f2bf(v);
  } else {
    int i = (blockIdx.x - 2048) * 256 + threadIdx.x;
    int c8 = (i & 63) * 8;
    int r = i >> 6;
    int b = r >> 9, l = r & 511;
    const float* s = src + ((size_t)b * 512 + l) * DMODEL + c8;
    float4 a = *(const float4*)s;
    float4 bq = *(const float4*)(s + 4);
    u16x8 o;
    o[0] = f2bf(a.x); o[1] = f2bf(a.y); o[2] = f2bf(a.z); o[3] = f2bf(a.w);
    o[4] = f2bf(bq.x); o[5] = f2bf(bq.y); o[6] = f2bf(bq.z); o[7] = f2bf(bq.w);
    *(u16x8*)&CATb[((size_t)b * 1024 + l) * DMODEL + c8] = o;
  }
}

// ---------------- MFMA GEMM 64x128 tile (bf16 A, bf16 W) ----------
// SPLIT: bf16 partials to Cb (+z*M*N).
template<int BK, int EPI, bool SPLIT, bool OUTB>
__global__ __launch_bounds__(256) void mgemmA(
    const unsigned short* __restrict__ A, const unsigned short* __restrict__ Bw,
    const float* __restrict__ bias, float* __restrict__ C,
    unsigned short* __restrict__ Cb, int M, int N, int K, int lda) {
  constexpr int PAD = BK + 8;
  constexpr int CHA = BK / 32;
  constexpr int CHB = BK / 16;
  __shared__ __align__(16) unsigned short As[64 * PAD];
  __shared__ __align__(16) unsigned short Bs[128 * PAD];
  const int tid = threadIdx.x;
  const int bn = blockIdx.x * 128;
  const int bm = blockIdx.y * 64;
  const int lane = tid & 63;
  const int w = tid >> 6;
  const int wr = (w >> 1) * 32;
  const int wc = (w & 1) * 64;
  const int l15 = lane & 15;
  const int l4 = lane >> 4;
  const int koff = l4 * 8;
  int kcnt = K, kbeg = 0;
  if (SPLIT) { kcnt = K / (int)gridDim.z; kbeg = blockIdx.z * kcnt; }
  const int nt = kcnt / BK;
  f32x4 acc[2][4] = {};

  int arow_[CHA], ak8_[CHA];
  const unsigned short* Ap[CHA];
#pragma unroll
  for (int i = 0; i < CHA; ++i) {
    int f = tid + 256 * i;
    arow_[i] = f / (BK / 8);
    ak8_[i] = (f % (BK / 8)) * 8;
    Ap[i] = A + (size_t)(bm + arow_[i]) * lda + kbeg + ak8_[i];
  }
  int brow_[CHB], bk8_[CHB];
  const unsigned short* Bp[CHB];
#pragma unroll
  for (int i = 0; i < CHB; ++i) {
    int f = tid + 256 * i;
    brow_[i] = f / (BK / 8);
    bk8_[i] = (f % (BK / 8)) * 8;
    Bp[i] = Bw + (size_t)(bn + brow_[i]) * K + kbeg + bk8_[i];
  }

  u16x8 av[CHA], bv[CHB];
#pragma unroll
  for (int i = 0; i < CHA; ++i) av[i] = *(const u16x8*)Ap[i];
#pragma unroll
  for (int i = 0; i < CHB; ++i) bv[i] = *(const u16x8*)Bp[i];

  for (int t = 0; t < nt; ++t) {
    __syncthreads();
#pragma unroll
    for (int i = 0; i < CHA; ++i) *(u16x8*)&As[arow_[i] * PAD + ak8_[i]] = av[i];
#pragma unroll
    for (int i = 0; i < CHB; ++i) *(u16x8*)&Bs[brow_[i] * PAD + bk8_[i]] = bv[i];
    if (t + 1 < nt) {
      int ko = (t + 1) * BK;
#pragma unroll
      for (int i = 0; i < CHA; ++i) av[i] = *(const u16x8*)(Ap[i] + ko);
#pragma unroll
      for (int i = 0; i < CHB; ++i) bv[i] = *(const u16x8*)(Bp[i] + ko);
    }
    __syncthreads();
#pragma unroll
    for (int kk = 0; kk < BK / 32; ++kk) {
      bf16x8 afr[2], bfr[4];
#pragma unroll
      for (int i = 0; i < 2; ++i)
        afr[i] = *(const bf16x8*)&As[(wr + i * 16 + l15) * PAD + kk * 32 + koff];
#pragma unroll
      for (int j = 0; j < 4; ++j)
        bfr[j] = *(const bf16x8*)&Bs[(wc + j * 16 + l15) * PAD + kk * 32 + koff];
#pragma unroll
      for (int fr = 0; fr < 2; ++fr)
#pragma unroll
        for (int fc = 0; fc < 4; ++fc)
          acc[fr][fc] = __builtin_amdgcn_mfma_f32_16x16x32_bf16(
              afr[fr], bfr[fc], acc[fr][fc], 0, 0, 0);
    }
  }

  if (SPLIT) {
    unsigned short* Pz = Cb + (size_t)blockIdx.z * M * N;
#pragma unroll
    for (int fc = 0; fc < 4; ++fc) {
      int col = bn + wc + fc * 16 + l15;
#pragma unroll
      for (int fr = 0; fr < 2; ++fr) {
        int row0 = bm + wr + fr * 16 + l4 * 4;
#pragma unroll
        for (int r = 0; r < 4; ++r)
          Pz[(size_t)(row0 + r) * N + col] = f2bf(acc[fr][fc][r]);
      }
    }
  } else {
#pragma unroll
    for (int fc = 0; fc < 4; ++fc) {
      int col = bn + wc + fc * 16 + l15;
      float bvs = (EPI != 0) ? bias[col] : 0.f;
#pragma unroll
      for (int fr = 0; fr < 2; ++fr) {
        int row0 = bm + wr + fr * 16 + l4 * 4;
#pragma unroll
        for (int r = 0; r < 4; ++r) {
          float v = epi_apply<EPI>(acc[fr][fc][r], bvs);
          if (OUTB) Cb[(size_t)(row0 + r) * N + col] = f2bf(v);
          else      C[(size_t)(row0 + r) * N + col] = v;
        }
      }
    }
  }
}

// ---------------- MFMA GEMM 64x64 tile (bf16 A, bf16 W) ----------------
// SPLIT: fp32 partials to C (+z*M*N)  (xproj path).
template<int BK, int EPI, bool SPLIT, bool OUTB>
__global__ __launch_bounds__(256) void mgemm(
    const unsigned short* __restrict__ A, const unsigned short* __restrict__ Bw,
    const float* __restrict__ bias, float* __restrict__ C,
    unsigned short* __restrict__ Cb, int M, int N, int K, int lda) {
  constexpr int PAD = BK + 8;
  constexpr int CH = BK / 32;
  __shared__ __align__(16) unsigned short As[64 * PAD];
  __shared__ __align__(16) unsigned short Bs[64 * PAD];
  const int tid = threadIdx.x;
  const int bn = blockIdx.x * 64;
  const int bm = blockIdx.y * 64;
  const int lane = tid & 63;
  const int w = tid >> 6;
  const int wr = (w >> 1) * 32;
  const int wc = (w & 1) * 32;
  const int l15 = lane & 15;
  const int l4 = lane >> 4;
  const int koff = l4 * 8;
  int kcnt = K, kbeg = 0;
  if (SPLIT) { kcnt = K / (int)gridDim.z; kbeg = blockIdx.z * kcnt; }
  const int nt = kcnt / BK;
  f32x4 acc[2][2] = {};

  int row_[CH], k8_[CH];
  const unsigned short *Ap[CH], *Bp[CH];
#pragma unroll
  for (int i = 0; i < CH; ++i) {
    int f = tid + 256 * i;
    row_[i] = f / (BK / 8);
    k8_[i] = (f % (BK / 8)) * 8;
    Ap[i] = A + (size_t)(bm + row_[i]) * lda + kbeg + k8_[i];
    Bp[i] = Bw + (size_t)(bn + row_[i]) * K + kbeg + k8_[i];
  }

  u16x8 av[CH], bv[CH];
#pragma unroll
  for (int i = 0; i < CH; ++i) { av[i] = *(const u16x8*)Ap[i]; bv[i] = *(const u16x8*)Bp[i]; }

  for (int t = 0; t < nt; ++t) {
    __syncthreads();
#pragma unroll
    for (int i = 0; i < CH; ++i) {
      *(u16x8*)&As[row_[i] * PAD + k8_[i]] = av[i];
      *(u16x8*)&Bs[row_[i] * PAD + k8_[i]] = bv[i];
    }
    if (t + 1 < nt) {
      int ko = (t + 1) * BK;
#pragma unroll
      for (int i = 0; i < CH; ++i) {
        av[i] = *(const u16x8*)(Ap[i] + ko);
        bv[i] = *(const u16x8*)(Bp[i] + ko);
      }
    }
    __syncthreads();
#pragma unroll
    for (int kk = 0; kk < CH; ++kk) {
      bf16x8 afr[2], bfr[2];
#pragma unroll
      for (int i = 0; i < 2; ++i) {
        afr[i] = *(const bf16x8*)&As[(wr + i * 16 + l15) * PAD + kk * 32 + koff];
        bfr[i] = *(const bf16x8*)&Bs[(wc + i * 16 + l15) * PAD + kk * 32 + koff];
      }
#pragma unroll
      for (int fr = 0; fr < 2; ++fr)
#pragma unroll
        for (int fc = 0; fc < 2; ++fc)
          acc[fr][fc] = __builtin_amdgcn_mfma_f32_16x16x32_bf16(
              afr[fr], bfr[fc], acc[fr][fc], 0, 0, 0);
    }
  }

  if (SPLIT) {
    float* Pz = C + (size_t)blockIdx.z * M * N;
#pragma unroll
    for (int fc = 0; fc < 2; ++fc) {
      int col = bn + wc + fc * 16 + l15;
#pragma unroll
      for (int fr = 0; fr < 2; ++fr) {
        int row0 = bm + wr + fr * 16 + l4 * 4;
#pragma unroll
        for (int r = 0; r < 4; ++r)
          Pz[(size_t)(row0 + r) * N + col] = acc[fr][fc][r];
      }
    }
  } else {
#pragma unroll
    for (int fc = 0; fc < 2; ++fc) {
      int col = bn + wc + fc * 16 + l15;
      float bvs = (EPI != 0) ? bias[col] : 0.f;
#pragma unroll
      for (int fr = 0; fr < 2; ++fr) {
        int row0 = bm + wr + fr * 16 + l4 * 4;
#pragma unroll
        for (int r = 0; r < 4; ++r) {
          float v = epi_apply<EPI>(acc[fr][fc][r], bvs);
          if (OUTB) Cb[(size_t)(row0 + r) * N + col] = f2bf(v);
          else      C[(size_t)(row0 + r) * N + col] = v;
        }
      }
    }
  }
}

// ---------------- causal depthwise conv (k=4) + bias + silu, 8 bf16/thread ------
__global__ __launch_bounds__(256) void conv_silu_kernel(
    const unsigned short* __restrict__ xzb, const float* __restrict__ w,
    const float* __restrict__ bias, unsigned short* __restrict__ outb, int L) {
  int idx = blockIdx.x * 256 + threadIdx.x;
  int d8 = (idx & 127) * 8;
  int bt = idx >> 7;
  int b = bt / L;
  int t = bt - b * L;
  const unsigned short* col = xzb + ((size_t)b * L) * (2 * DINNER) + d8;
  float acc[8];
  float4 wv[8];
#pragma unroll
  for (int j = 0; j < 8; ++j) {
    acc[j] = bias[d8 + j];
    wv[j] = *(const float4*)(w + (size_t)(d8 + j) * 4);
  }
#pragma unroll
  for (int k = 0; k < 4; ++k) {
    int tt = t - 3 + k;
    if (tt >= 0) {
      u16x8 v = *(const u16x8*)(col + (size_t)tt * (2 * DINNER));
      float wk[8] = {
        k == 0 ? wv[0].x : k == 1 ? wv[0].y : k == 2 ? wv[0].z : wv[0].w,
        k == 0 ? wv[1].x : k == 1 ? wv[1].y : k == 2 ? wv[1].z : wv[1].w,
        k == 0 ? wv[2].x : k == 1 ? wv[2].y : k == 2 ? wv[2].z : wv[2].w,
        k == 0 ? wv[3].x : k == 1 ? wv[3].y : k == 2 ? wv[3].z : wv[3].w,
        k == 0 ? wv[4].x : k == 1 ? wv[4].y : k == 2 ? wv[4].z : wv[4].w,
        k == 0 ? wv[5].x : k == 1 ? wv[5].y : k == 2 ? wv[5].z : wv[5].w,
        k == 0 ? wv[6].x : k == 1 ? wv[6].y : k == 2 ? wv[6].z : wv[6].w,
        k == 0 ? wv[7].x : k == 1 ? wv[7].y : k == 2 ? wv[7].z : wv[7].w };
#pragma unroll
      for (int j = 0; j < 8; ++j) acc[j] = fmaf(bf2f(v[j]), wk[j], acc[j]);
    }
  }
  u16x8 o;
#pragma unroll
  for (int j = 0; j < 8; ++j) {
    float sig = 1.f / (1.f + __expf(-acc[j]));
    o[j] = f2bf(acc[j] * sig);
  }
  *(u16x8*)&outb[(size_t)bt * DINNER + d8] = o;
}

// ---------------- chunked selective scan with inline dt-projection ----------------
__global__ __launch_bounds__(256) void scan_pass1(
    const float* __restrict__ XPP, const unsigned short* __restrict__ u,
    const float* __restrict__ Alog, const float* __restrict__ dtw,
    const float* __restrict__ dtb, float* __restrict__ P, float* __restrict__ S,
    int L, int CL) {
  __shared__ float DBL8[32][64];
  const int tid = threadIdx.x;
  const int d = blockIdx.x * 256 + tid;
  const int b = blockIdx.y;
  const int c = blockIdx.z;
  const int t0 = c * CL;
  if (tid < CL * 8) {
    int t = tid >> 3, j8 = (tid & 7) * 8;
    const float* p = XPP + ((size_t)b * L + t0 + t) * 64 + j8;
    const size_t zs = (size_t)BB * L * 64;
    float s[8] = {0.f, 0.f, 0.f, 0.f, 0.f, 0.f, 0.f, 0.f};
#pragma unroll
    for (int z = 0; z < 8; ++z) {
      float4 a = *(const float4*)(p + z * zs);
      float4 bq = *(const float4*)(p + z * zs + 4);
      s[0] += a.x; s[1] += a.y; s[2] += a.z; s[3] += a.w;
      s[4] += bq.x; s[5] += bq.y; s[6] += bq.z; s[7] += bq.w;
    }
#pragma unroll
    for (int j = 0; j < 8; ++j) DBL8[t][j8 + j] = s[j];
  }
  float A[16];
#pragma unroll
  for (int j = 0; j < 4; ++j) {
    float4 a4 = *(const float4*)(Alog + d * 16 + j * 4);
    A[j * 4 + 0] = -__expf(a4.x); A[j * 4 + 1] = -__expf(a4.y);
    A[j * 4 + 2] = -__expf(a4.z); A[j * 4 + 3] = -__expf(a4.w);
  }
  float wreg[32];
#pragma unroll
  for (int j = 0; j < 8; ++j) {
    float4 w4 = *(const float4*)(dtw + (size_t)d * 32 + j * 4);
    wreg[j*4+0] = w4.x; wreg[j*4+1] = w4.y; wreg[j*4+2] = w4.z; wreg[j*4+3] = w4.w;
  }
  float dtbv = dtb[d];
  float h[16], Pp[16];
#pragma unroll
  for (int n = 0; n < 16; ++n) { h[n] = 0.f; Pp[n] = 1.f; }
  const unsigned short* up = u + ((size_t)b * L + t0) * DINNER + d;
  __syncthreads();
  for (int t = 0; t < CL; ++t) {
    float dtraw = dtbv;
#pragma unroll
    for (int k8 = 0; k8 < 8; ++k8) {
      float4 q = *(const float4*)&DBL8[t][k8 * 4];
      dtraw = fmaf(q.x, wreg[k8*4+0], dtraw);
      dtraw = fmaf(q.y, wreg[k8*4+1], dtraw);
      dtraw = fmaf(q.z, wreg[k8*4+2], dtraw);
      dtraw = fmaf(q.w, wreg[k8*4+3], dtraw);
    }
    float dtv = fmaxf(dtraw, 0.f) + log1pf(__expf(-fabsf(dtraw)));
    float uv = bf2f(up[(size_t)t * DINNER]);
    float du = dtv * uv;
    float Bv[16];
#pragma unroll
    for (int j = 0; j < 4; ++j) {
      float4 b4 = *(const float4*)&DBL8[t][32 + j * 4];
      Bv[j*4+0] = b4.x; Bv[j*4+1] = b4.y; Bv[j*4+2] = b4.z; Bv[j*4+3] = b4.w;
    }
#pragma unroll
    for (int n = 0; n < 16; ++n) {
      float dA = __expf(dtv * A[n]);
      Pp[n] *= dA;
      h[n] = fmaf(dA, h[n], du * Bv[n]);
    }
  }
  size_t base = (size_t)c * 32768 + ((size_t)(b * 1024 + d) << 4);
#pragma unroll
  for (int j = 0; j < 4; ++j) {
    *(float4*)&P[base + j * 4] = make_float4(Pp[j*4], Pp[j*4+1], Pp[j*4+2], Pp[j*4+3]);
    *(float4*)&S[base + j * 4] = make_float4(h[j*4], h[j*4+1], h[j*4+2], h[j*4+3]);
  }
}

// pass2: inline dt + chunk-prefix; writes compact bf16 y.
__global__ __launch_bounds__(256) void scan_pass2(
    const float* __restrict__ XPP, const unsigned short* __restrict__ u,
    const unsigned short* __restrict__ xzb, const float* __restrict__ Alog,
    const float* __restrict__ dtw, const float* __restrict__ dtb,
    const float* __restrict__ Dsk, const float* __restrict__ P,
    const float* __restrict__ S, unsigned short* __restrict__ ysb,
    int L, int CL, int c0) {
  __shared__ float DBL8[32][64];
  const int tid = threadIdx.x;
  const int d = blockIdx.x * 256 + tid;
  const int b = blockIdx.y;
  const int c = blockIdx.z + c0;
  const int t0 = c * CL;
  if (tid < CL * 8) {
    int t = tid >> 3, j8 = (tid & 7) * 8;
    const float* p = XPP + ((size_t)b * L + t0 + t) * 64 + j8;
    const size_t zs = (size_t)BB * L * 64;
    float s[8] = {0.f, 0.f, 0.f, 0.f, 0.f, 0.f, 0.f, 0.f};
#pragma unroll
    for (int z = 0; z < 8; ++z) {
      float4 a = *(const float4*)(p + z * zs);
      float4 bq = *(const float4*)(p + z * zs + 4);
      s[0] += a.x; s[1] += a.y; s[2] += a.z; s[3] += a.w;
      s[4] += bq.x; s[5] += bq.y; s[6] += bq.z; s[7] += bq.w;
    }
#pragma unroll
    for (int j = 0; j < 8; ++j) DBL8[t][j8 + j] = s[j];
  }
  float A[16];
#pragma unroll
  for (int j = 0; j < 4; ++j) {
    float4 a4 = *(const float4*)(Alog + d * 16 + j * 4);
    A[j * 4 + 0] = -__expf(a4.x); A[j * 4 + 1] = -__expf(a4.y);
    A[j * 4 + 2] = -__expf(a4.z); A[j * 4 + 3] = -__expf(a4.w);
  }
  float wreg[32];
#pragma unroll
  for (int j = 0; j < 8; ++j) {
    float4 w4 = *(const float4*)(dtw + (size_t)d * 32 + j * 4);
    wreg[j*4+0] = w4.x; wreg[j*4+1] = w4.y; wreg[j*4+2] = w4.z; wreg[j*4+3] = w4.w;
  }
  float dtbv = dtb[d];
  float h[16];
#pragma unroll
  for (int n = 0; n < 16; ++n) h[n] = 0.f;
  size_t sbase = (size_t)(b * 1024 + d) << 4;
  for (int cc = 0; cc < c; ++cc) {
    size_t bb = (size_t)cc * 32768 + sbase;
#pragma unroll
    for (int j = 0; j < 4; ++j) {
      float4 p4 = *(const float4*)&P[bb + j * 4];
      float4 s4 = *(const float4*)&S[bb + j * 4];
      h[j*4+0] = fmaf(p4.x, h[j*4+0], s4.x);
      h[j*4+1] = fmaf(p4.y, h[j*4+1], s4.y);
      h[j*4+2] = fmaf(p4.z, h[j*4+2], s4.z);
      h[j*4+3] = fmaf(p4.w, h[j*4+3], s4.w);
    }
  }
  float Dv = Dsk[d];
  const unsigned short* up = u + ((size_t)b * L + t0) * DINNER + d;
  const unsigned short* zp = xzb + ((size_t)b * L + t0) * (2 * DINNER) + DINNER + d;
  unsigned short* yp = ysb + ((size_t)(b * 512) + (t0 - c0 * CL)) * DINNER + d;
  __syncthreads();
  for (int t = 0; t < CL; ++t) {
    float dtraw = dtbv;
#pragma unroll
    for (int k8 = 0; k8 < 8; ++k8) {
      float4 q = *(const float4*)&DBL8[t][k8 * 4];
      dtraw = fmaf(q.x, wreg[k8*4+0], dtraw);
      dtraw = fmaf(q.y, wreg[k8*4+1], dtraw);
      dtraw = fmaf(q.z, wreg[k8*4+2], dtraw);
      dtraw = fmaf(q.w, wreg[k8*4+3], dtraw);
    }
    float dtv = fmaxf(dtraw, 0.f) + log1pf(__expf(-fabsf(dtraw)));
    float uv = bf2f(up[(size_t)t * DINNER]);
    float zv = bf2f(zp[(size_t)t * (2 * DINNER)]);
    float du = dtv * uv;
    float Bv[16], Cv[16];
#pragma unroll
    for (int j = 0; j < 4; ++j) {
      float4 b4 = *(const float4*)&DBL8[t][32 + j * 4];
      float4 c4 = *(const float4*)&DBL8[t][48 + j * 4];
      Bv[j*4+0] = b4.x; Bv[j*4+1] = b4.y; Bv[j*4+2] = b4.z; Bv[j*4+3] = b4.w;
      Cv[j*4+0] = c4.x; Cv[j*4+1] = c4.y; Cv[j*4+2] = c4.z; Cv[j*4+3] = c4.w;
    }
    float y = 0.f;
#pragma unroll
    for (int n = 0; n < 16; ++n) {
      float dA = __expf(dtv * A[n]);
      h[n] = fmaf(dA, h[n], du * Bv[n]);
      y = fmaf(h[n], Cv[n], y);
    }
    float sig = 1.f / (1.f + __expf(-zv));
    yp[(size_t)t * DINNER] = f2bf((y + uv * Dv) * (zv * sig));
  }
}

// ---------------- fused split-K reduce (bf16 partials) + residual + LayerNorm ----
// FIN: additionally apply final LayerNorm and write fp32 d_out (skips X/outb).
template<int NZ, int EPI, bool FIN>
__global__ __launch_bounds__(64) void ln_red_kernel(
    const float* __restrict__ res, const unsigned short* __restrict__ Pb,
    const float* __restrict__ bias, const float* __restrict__ g,
    const float* __restrict__ be, float* __restrict__ out,
    unsigned short* __restrict__ outb, int row_scale, int row_off,
    const float* __restrict__ fing, const float* __restrict__ finb,
    float* __restrict__ fout) {
  int r = blockIdx.x;
  int b = r >> 9, t = r & 511;
  int lane = threadIdx.x;
  const float* rp = res + (size_t)r * DMODEL;
  size_t ob = ((size_t)(b * row_scale + row_off + t)) * DMODEL;
  float v[8];
  float s = 0.f, ss = 0.f;
#pragma unroll
  for (int j = 0; j < 8; ++j) {
    int col = lane + j * 64;
    float acc = 0.f;
#pragma unroll
    for (int z = 0; z < NZ; ++z)
      acc += bf2f(Pb[(size_t)z * 524288 + (size_t)r * DMODEL + col]);
    float bv = (EPI != 0) ? bias[col] : 0.f;
    float x = rp[col] + epi_apply<EPI>(acc, bv);
    v[j] = x; s += x; ss += x * x;
  }
#pragma unroll
  for (int o = 32; o > 0; o >>= 1) { s += __shfl_xor(s, o); ss += __shfl_xor(ss, o); }
  float m = s * (1.f / 512.f);
  float var = ss * (1.f / 512.f) - m * m;
  float rs = rsqrtf(var + 1e-6f);
  if (FIN) {
    float o2[8];
    float s2 = 0.f, ss2 = 0.f;
#pragma unroll
    for (int j = 0; j < 8; ++j) {
      int col = lane + j * 64;
      float x = (v[j] - m) * rs * g[col] + be[col];
      o2[j] = x; s2 += x; ss2 += x * x;
    }
#pragma unroll
    for (int o = 32; o > 0; o >>= 1) { s2 += __shfl_xor(s2, o); ss2 += __shfl_xor(ss2, o); }
    float m2 = s2 * (1.f / 512.f);
    float var2 = ss2 * (1.f / 512.f) - m2 * m2;
    float rs2 = rsqrtf(var2 + 1e-6f);
#pragma unroll
    for (int j = 0; j < 8; ++j) {
      int col = lane + j * 64;
      fout[(size_t)r * DMODEL + col] = (o2[j] - m2) * rs2 * fing[col] + finb[col];
    }
  } else {
#pragma unroll
    for (int j = 0; j < 8; ++j) {
      int col = lane + j * 64;
      float o2 = (v[j] - m) * rs * g[col] + be[col];
      out[(size_t)r * DMODEL + col] = o2;
      outb[ob + col] = f2bf(o2);
    }
  }
}

// ---------------- orchestration ----------------
extern "C" void kernel_launch(void* const* d_in, const int* in_sizes, int n_in,
                              void* d_out, int out_size, void* d_ws, size_t ws_size,
                              hipStream_t stream) {
  (void)in_sizes; (void)n_in; (void)out_size; (void)ws_size;
  const float* src      = (const float*)d_in[0];
  const int*   tgt      = (const int*)d_in[1];
  const float* emb      = (const float*)d_in[2];
  const float* in_w_s   = (const float*)d_in[3];
  const float* conv_w_s = (const float*)d_in[4];
  const float* conv_b_s = (const float*)d_in[5];
  const float* xproj_s  = (const float*)d_in[6];
  const float* dtw_s    = (const float*)d_in[7];
  const float* dtb_s    = (const float*)d_in[8];
  const float* Alog_s   = (const float*)d_in[9];
  const float* D_s      = (const float*)d_in[10];
  const float* outw_s   = (const float*)d_in[11];
  const float* in_w_c   = (const float*)d_in[12];
  const float* conv_w_c = (const float*)d_in[13];
  const float* conv_b_c = (const float*)d_in[14];
  const float* xproj_c  = (const float*)d_in[15];
  const float* dtw_c    = (const float*)d_in[16];
  const float* dtb_c    = (const float*)d_in[17];
  const float* Alog_c   = (const float*)d_in[18];
  const float* D_c      = (const float*)d_in[19];
  const float* outw_c   = (const float*)d_in[20];
  const float* ffn_w1   = (const float*)d_in[21];
  const float* ffn_b1   = (const float*)d_in[22];
  const float* ffn_w2   = (const float*)d_in[23];
  const float* ffn_b2   = (const float*)d_in[24];
  const float* ln_g     = (const float*)d_in[25];
  const float* ln_b     = (const float*)d_in[26];
  const float* fin_g    = (const float*)d_in[27];
  const float* fin_b    = (const float*)d_in[28];

  // ---- workspace layout ----
  float* ws   = (float*)d_ws;
  float* X    = ws;                   // 524288
  float* XPP  = X + 524288;           // 1048576 (xproj split-K partials, fp32)
  float* SC_P = XPP + 1048576;        // 1048576 (scan P)
  float* SC_S = SC_P + 1048576;       // 1048576 (scan S)
  unsigned short* U = (unsigned short*)(SC_S + 1048576);
  unsigned short* Xb   = U;                   // 524288
  unsigned short* CATb = Xb + 524288;         // 1048576
  unsigned short* XCb  = CATb + 1048576;      // 2097152
  unsigned short* XZb  = XCb + 2097152;       // 4194304
  unsigned short* YSb  = XZb + 4194304;       // 1048576
  unsigned short* XZPb = YSb + 1048576;       // 4194304 (out/ffn2 bf16 partials, z=8)
  unsigned short* WB   = XZPb + 4194304;
  unsigned short* inwsb = WB;                 // 6291456
  unsigned short* inwcb = inwsb + 6291456;    // 6291456
  unsigned short* xpsb  = inwcb + 6291456;    // 393216
  unsigned short* xpcb  = xpsb + 393216;      // 393216
  unsigned short* dtwsb = xpcb + 393216;      // 196608 (unused; cvt layout)
  unsigned short* dtwcb = dtwsb + 196608;     // 196608 (unused)
  unsigned short* owsb  = dtwcb + 196608;     // 3145728
  unsigned short* owcb  = owsb + 3145728;     // 3145728
  unsigned short* f1b   = owcb + 3145728;     // 6291456
  unsigned short* f2b   = f1b + 6291456;      // 6291456

  cvt_all_kernel<<<31872, 256, 0, stream>>>(
      in_w_s, in_w_c, xproj_s, xproj_c, dtw_s, dtw_c, outw_s, outw_c,
      ffn_w1, ffn_w2, WB);
  embed_cat_kernel<<<2304, 256, 0, stream>>>(tgt, emb, src, X, Xb, CATb);

  for (int i = 0; i < NLAYERS; ++i) {
    // ---------- self mamba (L = 512, CL = 16, 32 chunks) ----------
    mgemm<64, 0, false, true><<<dim3(32, 16), 256, 0, stream>>>(
        Xb, inwsb + (size_t)i * 1048576, nullptr, nullptr, XZb, 1024, 2048, 512, 512);
    conv_silu_kernel<<<512, 256, 0, stream>>>(
        XZb, conv_w_s + (size_t)i * 4096, conv_b_s + (size_t)i * 1024, XCb, 512);
    mgemm<64, 0, true, false><<<dim3(1, 16, 8), 256, 0, stream>>>(
        XCb, xpsb + (size_t)i * 65536, nullptr, XPP, nullptr, 1024, 64, 1024, 1024);
    scan_pass1<<<dim3(4, 2, 32), 256, 0, stream>>>(
        XPP, XCb, Alog_s + (size_t)i * 16384, dtw_s + (size_t)i * 32768,
        dtb_s + (size_t)i * 1024, SC_P, SC_S, 512, 16);
    scan_pass2<<<dim3(4, 2, 32), 256, 0, stream>>>(
        XPP, XCb, XZb, Alog_s + (size_t)i * 16384, dtw_s + (size_t)i * 32768,
        dtb_s + (size_t)i * 1024, D_s + (size_t)i * 1024, SC_P, SC_S, YSb, 512, 16, 0);
    mgemmA<64, 0, true, false><<<dim3(4, 16, 8), 256, 0, stream>>>(
        YSb, owsb + (size_t)i * 524288, nullptr, nullptr, XZPb, 1024, 512, 1024, 1024);
    ln_red_kernel<8, 0, false><<<1024, 64, 0, stream>>>(
        X, XZPb, nullptr, ln_g + (size_t)(i * 3 + 0) * 512,
        ln_b + (size_t)(i * 3 + 0) * 512, X, CATb, 1024, 512,
        nullptr, nullptr, nullptr);

    // ---------- cross mamba (L = 1024, CL = 32; y for last 512 t only) ----------
    mgemmA<64, 0, false, true><<<dim3(16, 32), 256, 0, stream>>>(
        CATb, inwcb + (size_t)i * 1048576, nullptr, nullptr, XZb, 2048, 2048, 512, 512);
    conv_silu_kernel<<<1024, 256, 0, stream>>>(
        XZb, conv_w_c + (size_t)i * 4096, conv_b_c + (size_t)i * 1024, XCb, 1024);
    mgemm<64, 0, true, false><<<dim3(1, 32, 8), 256, 0, stream>>>(
        XCb, xpcb + (size_t)i * 65536, nullptr, XPP, nullptr, 2048, 64, 1024, 1024);
    scan_pass1<<<dim3(4, 2, 32), 256, 0, stream>>>(
        XPP, XCb, Alog_c + (size_t)i * 16384, dtw_c + (size_t)i * 32768,
        dtb_c + (size_t)i * 1024, SC_P, SC_S, 1024, 32);
    scan_pass2<<<dim3(4, 2, 16), 256, 0, stream>>>(
        XPP, XCb, XZb, Alog_c + (size_t)i * 16384, dtw_c + (size_t)i * 32768,
        dtb_c + (size_t)i * 1024, D_c + (size_t)i * 1024, SC_P, SC_S, YSb, 1024, 32, 16);
    mgemmA<64, 0, true, false><<<dim3(4, 16, 8), 256, 0, stream>>>(
        YSb, owcb + (size_t)i * 524288, nullptr, nullptr, XZPb, 1024, 512, 1024, 1024);
    ln_red_kernel<8, 0, false><<<1024, 64, 0, stream>>>(
        X, XZPb, nullptr, ln_g + (size_t)(i * 3 + 1) * 512,
        ln_b + (size_t)(i * 3 + 1) * 512, X, Xb, 512, 0,
        nullptr, nullptr, nullptr);

    // ---------- FFN ----------
    mgemm<64, 1, false, true><<<dim3(32, 16), 256, 0, stream>>>(
        Xb, f1b + (size_t)i * 1048576, ffn_b1 + (size_t)i * 2048, nullptr, XZb,
        1024, 2048, 512, 512);
    mgemmA<64, 0, true, false><<<dim3(4, 16, 8), 256, 0, stream>>>(
        XZb, f2b + (size_t)i * 1048576, nullptr, nullptr, XZPb, 1024, 512, 2048, 2048);
    if (i < NLAYERS - 1) {
      ln_red_kernel<8, 2, false><<<1024, 64, 0, stream>>>(
          X, XZPb, ffn_b2 + (size_t)i * 512, ln_g + (size_t)(i * 3 + 2) * 512,
          ln_b + (size_t)(i * 3 + 2) * 512, X, Xb, 512, 0,
          nullptr, nullptr, nullptr);
    } else {
      ln_red_kernel<8, 2, true><<<1024, 64, 0, stream>>>(
          X, XZPb, ffn_b2 + (size_t)i * 512, ln_g + (size_t)(i * 3 + 2) * 512,
          ln_b + (size_t)(i * 3 + 2) * 512, nullptr, nullptr, 512, 0,
          fin_g, fin_b, (float*)d_out);
    }
  }
}